// Round 4
// baseline (34.828 us; speedup 1.0000x reference)
//
#include <hip/hip_runtime.h>

// 3D MRoPE cos/sin table builder — stream-split variant.
// Output: cos [131072,192] fp32 then sin [131072,192] fp32, flat.
// Row p = t*4096 + y*64 + x (T=32, H=64, W=64).
//   d in [0,64):    angle = t * inv_freq_t[d & 31]
//   d in [64,128):  angle = y * inv_freq_y[(d-64) & 31]
//   d in [128,192): angle = x * inv_freq_x[(d-128) & 31]
//
// R4 A/B: block-split streams. Blocks [0,1536) write the cos half only,
// blocks [1536,3072) the sin half only — each wave emits ONE sequential
// store stream (fillBuffer's pattern) instead of alternating between two
// streams 100 MB apart. Per-half thread count 393216 = 48*8192: dv/seg/
// inv_freq stay loop-invariant, p advances 8192/iter, 16 iters, no tail.

#define T_FRAMES 32
#define HGT 64
#define WID 64
#define NPOS (T_FRAMES * HGT * WID)  // 131072
#define DIMC 192
#define HALF_BLOCKS 1536
#define HALF_THREADS (HALF_BLOCKS * 256)  // 393216 = 48 * 8192
#define ITERS 16                          // 6291456 / 393216

typedef float f4v __attribute__((ext_vector_type(4)));

__global__ __launch_bounds__(256) void mrope_split(
    const float* __restrict__ ift,
    const float* __restrict__ ify,
    const float* __restrict__ ifx,
    float* __restrict__ out)
{
    const int bid = blockIdx.x;
    const bool do_sin = bid >= HALF_BLOCKS;
    f4v* __restrict__ o = (f4v*)(out + (do_sin ? (size_t)NPOS * DIMC : 0));

    const int v0 = (bid - (do_sin ? HALF_BLOCKS : 0)) * blockDim.x + threadIdx.x;
    const int dv = v0 % 48;          // float4 index within row — loop-invariant
    int p       = v0 / 48;           // row; advances by 8192 per iteration
    const int seg = dv >> 4;         // 0=t, 1=y, 2=x — loop-invariant

    const float* invf = (seg == 0) ? ift : (seg == 1) ? ify : ifx;
    const f4v fr = ((const f4v*)invf)[dv & 7];   // j = (dv&7)*4+k, hoisted

    int v = v0;
    #pragma unroll 4
    for (int k = 0; k < ITERS; ++k) {
        int coord;
        if (seg == 0)      coord = p >> 12;        // t
        else if (seg == 1) coord = (p >> 6) & 63;  // y
        else               coord = p & 63;         // x
        float cf = (float)coord;
        float a0 = cf * fr.x, a1 = cf * fr.y, a2 = cf * fr.z, a3 = cf * fr.w;
        f4v r;
        if (do_sin) {
            r.x = __sinf(a0); r.y = __sinf(a1); r.z = __sinf(a2); r.w = __sinf(a3);
        } else {
            r.x = __cosf(a0); r.y = __cosf(a1); r.z = __cosf(a2); r.w = __cosf(a3);
        }
        o[v] = r;                    // single sequential stream per wave
        v += HALF_THREADS;
        p += HALF_THREADS / 48;      // 8192
    }
}

extern "C" void kernel_launch(void* const* d_in, const int* in_sizes, int n_in,
                              void* d_out, int out_size, void* d_ws, size_t ws_size,
                              hipStream_t stream) {
    // d_in[0] = x (unused); [1]=inv_freq_t, [2]=inv_freq_y, [3]=inv_freq_x
    const float* ift = (const float*)d_in[1];
    const float* ify = (const float*)d_in[2];
    const float* ifx = (const float*)d_in[3];
    mrope_split<<<2 * HALF_BLOCKS, 256, 0, stream>>>(ift, ify, ifx, (float*)d_out);
}